// Round 10
// baseline (408.978 us; speedup 1.0000x reference)
//
#include <hip/hip_runtime.h>

// GraphPolicyNetwork: 2-layer GraphSAGE (rank-1 weights -> scalar edge passes)
// + dense head [64x4096]@[4096x4096]. All tensors fp32 (proven round 4).
//
// R9 post-mortem: global atomics hit a ~19 G/s RMW wall with 32 B fabric
// write-through EACH, regardless of scope (R4 device-scope 19.4 G/s; R9
// workgroup-scope XCD-replica 18.9 G/s, WRITE_SIZE 65.5 MB = 2M x 32 B).
// ~210 us of the 405 was pure atomic throughput. Fix: atomic-free edge
// aggregation -- partition edges into 32 dst-range buckets (8192 nodes,
// packed u32 record: (dst&8191)<<18 | src), then per-bucket LDS histogram
// (ds_add_f32) + non-atomic partial flush; partial reduction folded into
// node1/node2. GEMM (R9's readfirstlane + dbuf version, proven) unchanged.
// Fast path needs 20 MB d_ws; falls back to proven R4 pipeline if smaller.

#define NTOT (64 * 4096)      // 262144 total nodes = 2^18
#define NHID 128
#define GK   4096             // GEMM K == N_NODES
#define KCH  256              // K per chunk
#define KCHUNKS 16
#define NBINS 32              // dst-range buckets
#define BSZ   8192            // nodes per bucket (2^13)
#define NSL   4               // slices (blocks) per bucket in agg kernels
#define PBLK  256             // partition blocks

typedef unsigned int u32;

__device__ __forceinline__ float fast_tanh(float x) {
    float ax = fabsf(x);
    float t  = __expf(-2.0f * ax);
    float r  = (1.0f - t) / (1.0f + t);
    return copysignf(r, x);
}

// ======================= FAST PATH (ws >= 20 MB) ==========================

// ---- P1: per-block per-bucket edge counts ----
__global__ void part_count(const int* __restrict__ dst, int n_edges,
                           int* __restrict__ counts /*[PBLK][NBINS]*/) {
    __shared__ int c[NBINS];
    int t = threadIdx.x;
    if (t < NBINS) c[t] = 0;
    __syncthreads();
    int per = (n_edges + gridDim.x - 1) / gridDim.x;
    int e0 = blockIdx.x * per;
    int e1 = min(e0 + per, n_edges);
    for (int e = e0 + t; e < e1; e += blockDim.x)
        atomicAdd(&c[dst[e] >> 13], 1);
    __syncthreads();
    if (t < NBINS) counts[blockIdx.x * NBINS + t] = c[t];
}

// ---- P2: prefix-scan counts -> per-block write offsets + bucket starts ----
// launch <<<1, 32>>>: thread b owns bucket b.
__global__ void part_scan(const int* __restrict__ counts, int* __restrict__ offsets,
                          int* __restrict__ bstart, int nblk) {
    int b = threadIdx.x;
    int run = 0;
    for (int blk = 0; blk < nblk; ++blk) {
        offsets[blk * NBINS + b] = run;
        run += counts[blk * NBINS + b];
    }
    __shared__ int tl[NBINS];
    tl[b] = run;
    __syncthreads();
    int pre = 0;
    for (int i = 0; i < b; ++i) pre += tl[i];
    bstart[b] = pre;
    if (b == NBINS - 1) bstart[NBINS] = pre + run;
    for (int blk = 0; blk < nblk; ++blk) offsets[blk * NBINS + b] += pre;
}

// ---- P3: scatter packed edge records into bucket segments ----
__global__ void part_scatter(const int* __restrict__ src, const int* __restrict__ dst,
                             int n_edges, const int* __restrict__ offsets,
                             u32* __restrict__ packed) {
    __shared__ int loff[NBINS];
    int t = threadIdx.x;
    if (t < NBINS) loff[t] = offsets[blockIdx.x * NBINS + t];
    __syncthreads();
    int per = (n_edges + gridDim.x - 1) / gridDim.x;
    int e0 = blockIdx.x * per;
    int e1 = min(e0 + per, n_edges);
    for (int e = e0 + t; e < e1; e += blockDim.x) {
        int d = dst[e];
        int pos = atomicAdd(&loff[d >> 13], 1);   // LDS atomic
        packed[pos] = ((u32)(d & (BSZ - 1)) << 18) | (u32)src[e];
    }
}

// ---- agg1: LDS histogram (sum of nf[src], count) per bucket slice ----
__global__ void __launch_bounds__(256) agg_pass1(const u32* __restrict__ packed,
                                                 const int* __restrict__ bstart,
                                                 const float* __restrict__ nf,
                                                 float* __restrict__ part1) {
    __shared__ float lsum[BSZ];
    __shared__ float lcnt[BSZ];
    int t = threadIdx.x;
    int b = blockIdx.x, s = blockIdx.y;
    for (int i = t; i < BSZ; i += 256) { lsum[i] = 0.0f; lcnt[i] = 0.0f; }
    __syncthreads();
    int st = bstart[b], en = bstart[b + 1];
    int per = (en - st + NSL - 1) / NSL;
    int e0 = st + s * per;
    int e1 = min(e0 + per, en);
    for (int e = e0 + t; e < e1; e += 256) {
        u32 p = packed[e];
        int local = (int)(p >> 18);
        int sc    = (int)(p & 0x3FFFFu);
        atomicAdd(&lsum[local], nf[sc]);
        atomicAdd(&lcnt[local], 1.0f);
    }
    __syncthreads();
    float* dp = part1 + ((size_t)(b * NSL + s) * 2) * BSZ;
    for (int i = t; i < BSZ; i += 256) { dp[i] = lsum[i]; dp[BSZ + i] = lcnt[i]; }
}

// ---- node1: reduce partials -> deg, hn; compute selfp, sp ----
__global__ void node1_x(const float* __restrict__ nf, const float* __restrict__ part1,
                        const float* __restrict__ w_s1, const float* __restrict__ w_n1,
                        const float* __restrict__ bb1,
                        const float* __restrict__ w_s2, const float* __restrict__ w_n2,
                        float* __restrict__ degf, float* __restrict__ selfp,
                        float* __restrict__ sp) {
    __shared__ float lws1[NHID], lwn1[NHID], lb1[NHID], lws2[NHID], lwn2[NHID];
    int tid = threadIdx.x;
    if (tid < NHID) {
        lws1[tid] = w_s1[tid];
        lwn1[tid] = w_n1[tid];
        lb1[tid]  = bb1[tid];
        lws2[tid] = w_s2[tid];
        lwn2[tid] = w_n2[tid];
    }
    __syncthreads();
    int v = blockIdx.x * blockDim.x + tid;
    int b = v >> 13, local = v & (BSZ - 1);
    float sum = 0.0f, cf = 0.0f;
#pragma unroll
    for (int s = 0; s < NSL; ++s) {
        const float* dp = part1 + ((size_t)(b * NSL + s) * 2) * BSZ;
        sum += dp[local];
        cf  += dp[BSZ + local];
    }
    float hn = sum / fmaxf(cf, 1.0f);
    float f = nf[v];
    float a = 0.0f, s2 = 0.0f;
#pragma unroll 8
    for (int j = 0; j < NHID; ++j) {
        float t = fast_tanh(fmaf(f, lws1[j], fmaf(hn, lwn1[j], lb1[j])));
        a  = fmaf(t, lws2[j], a);
        s2 = fmaf(t, lwn2[j], s2);
    }
    degf[v]  = cf;
    selfp[v] = a;
    sp[v]    = s2;
}

// ---- agg2: LDS histogram (sum of sp[src]) per bucket slice ----
__global__ void __launch_bounds__(256) agg_pass2(const u32* __restrict__ packed,
                                                 const int* __restrict__ bstart,
                                                 const float* __restrict__ spv,
                                                 float* __restrict__ part2) {
    __shared__ float lsum[BSZ];
    int t = threadIdx.x;
    int b = blockIdx.x, s = blockIdx.y;
    for (int i = t; i < BSZ; i += 256) lsum[i] = 0.0f;
    __syncthreads();
    int st = bstart[b], en = bstart[b + 1];
    int per = (en - st + NSL - 1) / NSL;
    int e0 = st + s * per;
    int e1 = min(e0 + per, en);
    for (int e = e0 + t; e < e1; e += 256) {
        u32 p = packed[e];
        atomicAdd(&lsum[p >> 18], spv[p & 0x3FFFFu]);
    }
    __syncthreads();
    float* dp = part2 + (size_t)(b * NSL + s) * BSZ;
    for (int i = t; i < BSZ; i += 256) dp[i] = lsum[i];
}

// ---- node2: reduce partials2; out1 (fp32); h2t K-major ----
__global__ void node2_x(const float* __restrict__ selfp, const float* __restrict__ part2,
                        const float* __restrict__ degf, const float* __restrict__ b2p,
                        float* __restrict__ out1, float* __restrict__ h2t) {
    int v = blockIdx.x * blockDim.x + threadIdx.x;
    int b = v >> 13, local = v & (BSZ - 1);
    float agg2 = 0.0f;
#pragma unroll
    for (int s = 0; s < NSL; ++s)
        agg2 += part2[(size_t)(b * NSL + s) * BSZ + local];
    float o = selfp[v] + agg2 / fmaxf(degf[v], 1.0f) + b2p[0];
    out1[v] = o;
    int r = v >> 12;     // graph (row) index 0..63
    int k = v & 4095;    // node-in-graph (K) index
    h2t[k * 64 + r] = fast_tanh(o);
}

// ---- GEMM (proven R9): 64x64 tile, readfirstlane A, dbuf A+B prefetch ----
__global__ void __launch_bounds__(256, 2) gemm_x(const float* __restrict__ h2t,
                                                 const float* __restrict__ w3,
                                                 float* __restrict__ Cpart) {
    int lane = threadIdx.x & 63;
    int wv   = threadIdx.x >> 6;
    int col  = blockIdx.x * 64 + lane;
    int k0   = blockIdx.y * KCH;
    int row0 = __builtin_amdgcn_readfirstlane(wv * 16);

    const float* Ap = h2t + (size_t)k0 * 64 + row0;
    const float* wp = w3 + (size_t)k0 * GK + col;

    float acc[16];
#pragma unroll
    for (int r = 0; r < 16; ++r) acc[r] = 0.0f;

    float bvA[8], bvB[8];
    float avA[16], avB[16];

#pragma unroll
    for (int j = 0; j < 8; ++j) bvA[j] = wp[(size_t)j * GK];
#pragma unroll
    for (int r = 0; r < 16; ++r) avA[r] = Ap[r];

    for (int kk = 0; kk < KCH; kk += 16) {
#pragma unroll
        for (int j = 0; j < 8; ++j) bvB[j] = wp[(size_t)(kk + 8 + j) * GK];
#pragma unroll
        for (int j = 0; j < 8; ++j) {
            const float* An = Ap + (size_t)(kk + j + 1) * 64;
            if ((j & 1) == 0) {
#pragma unroll
                for (int r = 0; r < 16; ++r) avB[r] = An[r];
                float b = bvA[j];
#pragma unroll
                for (int r = 0; r < 16; ++r) acc[r] = fmaf(avA[r], b, acc[r]);
            } else {
#pragma unroll
                for (int r = 0; r < 16; ++r) avA[r] = An[r];
                float b = bvA[j];
#pragma unroll
                for (int r = 0; r < 16; ++r) acc[r] = fmaf(avB[r], b, acc[r]);
            }
        }
        if (kk + 16 < KCH) {
#pragma unroll
            for (int j = 0; j < 8; ++j) bvA[j] = wp[(size_t)(kk + 16 + j) * GK];
        }
#pragma unroll
        for (int j = 0; j < 8; ++j) {
            int kn = kk + 8 + j + 1;
            if (kn > KCH - 1) kn = KCH - 1;
            const float* An = Ap + (size_t)kn * 64;
            if ((j & 1) == 0) {
#pragma unroll
                for (int r = 0; r < 16; ++r) avB[r] = An[r];
                float b = bvB[j];
#pragma unroll
                for (int r = 0; r < 16; ++r) acc[r] = fmaf(avA[r], b, acc[r]);
            } else {
#pragma unroll
                for (int r = 0; r < 16; ++r) avA[r] = An[r];
                float b = bvB[j];
#pragma unroll
                for (int r = 0; r < 16; ++r) acc[r] = fmaf(avB[r], b, acc[r]);
            }
        }
    }

    float* Cp = Cpart + (size_t)blockIdx.y * NTOT + (size_t)row0 * GK + col;
#pragma unroll
    for (int r = 0; r < 16; ++r) Cp[(size_t)r * GK] = acc[r];
}

// ---- reduce K-chunk partials + b3 -> out2 ----
__global__ void reduce_x(const float* __restrict__ Cpart, const float* __restrict__ b3,
                         float* __restrict__ out2) {
    int v = blockIdx.x * blockDim.x + threadIdx.x;
    float s = b3[v & 4095];
#pragma unroll
    for (int kc = 0; kc < KCHUNKS; ++kc) s += Cpart[(size_t)kc * NTOT + v];
    out2[v] = s;
}

// ================== FALLBACK PATH (proven R4 pipeline) ====================

__global__ void edge_pass1_f(const int* __restrict__ src, const int* __restrict__ dst,
                             const float* __restrict__ nf, float* __restrict__ agg,
                             float* __restrict__ deg, int n_edges) {
    int e = blockIdx.x * blockDim.x + threadIdx.x;
    if (e >= n_edges) return;
    int s = src[e], d = dst[e];
    atomicAdd(&agg[d], nf[s]);
    atomicAdd(&deg[d], 1.0f);
}

__global__ void node1_f(const float* __restrict__ nf, float* s0,
                        const float* __restrict__ deg,
                        const float* __restrict__ w_s1, const float* __restrict__ w_n1,
                        const float* __restrict__ bb1,
                        const float* __restrict__ w_s2, const float* __restrict__ w_n2,
                        float* __restrict__ sp) {
    __shared__ float lws1[NHID], lwn1[NHID], lb1[NHID], lws2[NHID], lwn2[NHID];
    int tid = threadIdx.x;
    if (tid < NHID) {
        lws1[tid] = w_s1[tid];
        lwn1[tid] = w_n1[tid];
        lb1[tid]  = bb1[tid];
        lws2[tid] = w_s2[tid];
        lwn2[tid] = w_n2[tid];
    }
    __syncthreads();
    int v = blockIdx.x * blockDim.x + tid;
    float f  = nf[v];
    float hn = s0[v] / fmaxf(deg[v], 1.0f);
    float a = 0.0f, s = 0.0f;
#pragma unroll 8
    for (int j = 0; j < NHID; ++j) {
        float t = fast_tanh(fmaf(f, lws1[j], fmaf(hn, lwn1[j], lb1[j])));
        a = fmaf(t, lws2[j], a);
        s = fmaf(t, lwn2[j], s);
    }
    s0[v] = a;
    sp[v] = s;
}

__global__ void edge_pass2_f(const int* __restrict__ src, const int* __restrict__ dst,
                             const float* __restrict__ sp, float* __restrict__ agg2,
                             int n_edges) {
    int e = blockIdx.x * blockDim.x + threadIdx.x;
    if (e >= n_edges) return;
    atomicAdd(&agg2[dst[e]], sp[src[e]]);
}

__global__ void node2_f(const float* __restrict__ s0, const float* __restrict__ agg2,
                        const float* __restrict__ deg, const float* __restrict__ b2p,
                        const float* __restrict__ b3p,
                        float* __restrict__ out1, float* __restrict__ h2t,
                        float* __restrict__ out2) {
    int v = blockIdx.x * blockDim.x + threadIdx.x;
    float o = s0[v] + agg2[v] / fmaxf(deg[v], 1.0f) + b2p[0];
    out1[v] = o;
    int r = v >> 12;
    int k = v & 4095;
    h2t[k * 64 + r] = fast_tanh(o);
    out2[v] = b3p[v & 4095];
}

__global__ void __launch_bounds__(256) gemm_f(const float* __restrict__ h2t,
                                              const float* __restrict__ w3,
                                              float* __restrict__ out2) {
    int n  = blockIdx.x * 256 + threadIdx.x;
    int k0 = blockIdx.y * KCH;
    float acc[64];
#pragma unroll
    for (int r = 0; r < 64; ++r) acc[r] = 0.0f;
    for (int k = k0; k < k0 + KCH; ++k) {
        float bv = w3[(size_t)k * GK + n];
        const float* Ak = h2t + k * 64;
#pragma unroll
        for (int r = 0; r < 64; ++r) acc[r] = fmaf(Ak[r], bv, acc[r]);
    }
#pragma unroll
    for (int r = 0; r < 64; ++r) atomicAdd(&out2[r * GK + n], acc[r]);
}

// ==========================================================================

extern "C" void kernel_launch(void* const* d_in, const int* in_sizes, int n_in,
                              void* d_out, int out_size, void* d_ws, size_t ws_size,
                              hipStream_t stream) {
    const float* nf  = (const float*)d_in[0];
    const int*   src = (const int*)d_in[1];
    const int*   dst = (const int*)d_in[2];
    const float* ws1 = (const float*)d_in[3];
    const float* wn1 = (const float*)d_in[4];
    const float* b1  = (const float*)d_in[5];
    const float* ws2 = (const float*)d_in[6];
    const float* wn2 = (const float*)d_in[7];
    const float* b2  = (const float*)d_in[8];
    const float* w3  = (const float*)d_in[9];
    const float* b3  = (const float*)d_in[10];
    float* out1 = (float*)d_out;
    float* out2 = (float*)d_out + NTOT;

    int n_edges = in_sizes[1];
    int eb = (n_edges + 255) / 256;

    if (ws_size >= (size_t)20 * 1024 * 1024 && n_edges <= (1 << 21)) {
        // -------- fast path: 20 MB layout --------
        char* base = (char*)d_ws;
        u32*   packed = (u32*)base;                              // [0, 8 MB)
        float* part   = (float*)(base + (((size_t)8) << 20));    // [8, 16 MB)
        float* degf   = (float*)(base + (((size_t)16) << 20));   // 1 MB
        float* selfp  = (float*)(base + (((size_t)17) << 20));   // 1 MB
        float* spbuf  = (float*)(base + (((size_t)18) << 20));   // sp -> h2t
        int*   counts = (int*)(base + (((size_t)19) << 20));           // 32 KB
        int*   offs   = (int*)(base + (((size_t)19) << 20) + 32768);   // 32 KB
        int*   bstart = (int*)(base + (((size_t)19) << 20) + 65536);   // 132 B
        float* h2t    = spbuf;          // alias: sp dead after agg_pass2
        float* Cpart  = (float*)base;   // 16 MB: packed+part dead after node2

        part_count  <<<PBLK, 256, 0, stream>>>(dst, n_edges, counts);
        part_scan   <<<1, 32, 0, stream>>>(counts, offs, bstart, PBLK);
        part_scatter<<<PBLK, 256, 0, stream>>>(src, dst, n_edges, offs, packed);
        agg_pass1<<<dim3(NBINS, NSL), 256, 0, stream>>>(packed, bstart, nf, part);
        node1_x<<<NTOT / 256, 256, 0, stream>>>(nf, part, ws1, wn1, b1, ws2, wn2,
                                                degf, selfp, spbuf);
        agg_pass2<<<dim3(NBINS, NSL), 256, 0, stream>>>(packed, bstart, spbuf, part);
        node2_x<<<NTOT / 256, 256, 0, stream>>>(selfp, part, degf, b2, out1, h2t);
        gemm_x<<<dim3(GK / 64, KCHUNKS), 256, 0, stream>>>(h2t, w3, Cpart);
        reduce_x<<<NTOT / 256, 256, 0, stream>>>(Cpart, b3, out2);
    } else {
        // -------- fallback: proven R4 pipeline (4.19 MB) --------
        float* ws = (float*)d_ws;
        float* S0 = ws;            // agg -> selfpart
        float* S1 = ws + 1 * NTOT; // deg
        float* S2 = ws + 2 * NTOT; // agg2
        float* S3 = ws + 3 * NTOT; // sp -> h2t

        (void)hipMemsetAsync(S0, 0, (size_t)3 * NTOT * sizeof(float), stream);
        edge_pass1_f<<<eb, 256, 0, stream>>>(src, dst, nf, S0, S1, n_edges);
        node1_f<<<NTOT / 256, 256, 0, stream>>>(nf, S0, S1, ws1, wn1, b1, ws2, wn2, S3);
        edge_pass2_f<<<eb, 256, 0, stream>>>(src, dst, S3, S2, n_edges);
        node2_f<<<NTOT / 256, 256, 0, stream>>>(S0, S2, S1, b2, b3, out1, S3, out2);
        gemm_f<<<dim3(GK / 256, KCHUNKS), 256, 0, stream>>>(S3, w3, out2);
    }
}

// Round 11
// 316.343 us; speedup vs baseline: 1.2928x; 1.2928x over previous
//
#include <hip/hip_runtime.h>

// GraphPolicyNetwork: 2-layer GraphSAGE (rank-1 weights -> scalar edge passes)
// + dense head [64x4096]@[4096x4096]. All tensors fp32 (proven round 4).
//
// R10 post-mortem: atomic-free LDS-histogram aggregation works (edge/agg
// passes off top-5), but part_scan was a 32-thread SERIAL scan: 256
// dependent global loads x ~900 cyc = 97 us on one CU. This round: parallel
// single-block scan (32 bins x 32 chunks x 8 counts; LDS tree), depth ~8
// independent loads + 64 LDS ops. Everything else identical to R10.
// Fast path needs 20 MB d_ws; falls back to proven R4 pipeline if smaller.

#define NTOT (64 * 4096)      // 262144 total nodes = 2^18
#define NHID 128
#define GK   4096             // GEMM K == N_NODES
#define KCH  256              // K per chunk
#define KCHUNKS 16
#define NBINS 32              // dst-range buckets
#define BSZ   8192            // nodes per bucket (2^13)
#define NSL   4               // slices (blocks) per bucket in agg kernels
#define PBLK  256             // partition blocks

typedef unsigned int u32;

__device__ __forceinline__ float fast_tanh(float x) {
    float ax = fabsf(x);
    float t  = __expf(-2.0f * ax);
    float r  = (1.0f - t) / (1.0f + t);
    return copysignf(r, x);
}

// ======================= FAST PATH (ws >= 20 MB) ==========================

// ---- P1: per-block per-bucket edge counts ----
__global__ void part_count(const int* __restrict__ dst, int n_edges,
                           int* __restrict__ counts /*[PBLK][NBINS]*/) {
    __shared__ int c[NBINS];
    int t = threadIdx.x;
    if (t < NBINS) c[t] = 0;
    __syncthreads();
    int per = (n_edges + gridDim.x - 1) / gridDim.x;
    int e0 = blockIdx.x * per;
    int e1 = min(e0 + per, n_edges);
    for (int e = e0 + t; e < e1; e += blockDim.x)
        atomicAdd(&c[dst[e] >> 13], 1);
    __syncthreads();
    if (t < NBINS) counts[blockIdx.x * NBINS + t] = c[t];
}

// ---- P2: PARALLEL scan: 1 block, 1024 threads = 32 bins x 32 chunks ----
// chunk ch owns blocks [8ch, 8ch+8). offsets[blk][b] = bstart[b] +
// sum_{blk'<blk} counts[blk'][b]. Depth: 8 indep loads + 2 LDS serial-32.
__global__ void __launch_bounds__(1024) part_scan(const int* __restrict__ counts,
                                                  int* __restrict__ offsets,
                                                  int* __restrict__ bstart) {
    __shared__ int csum[32][NBINS + 1];   // [chunk][bin], padded
    __shared__ int tot[NBINS];
    __shared__ int binbase[NBINS + 1];
    int t  = threadIdx.x;
    int b  = t & 31;
    int ch = t >> 5;

    int c[8];
    int s = 0;
#pragma unroll
    for (int i = 0; i < 8; ++i) {
        c[i] = counts[(ch * 8 + i) * NBINS + b];   // coalesced, independent
        s += c[i];
    }
    csum[ch][b] = s;
    __syncthreads();

    if (ch == 0) {            // thread b: serial scan of 32 chunk-sums (LDS)
        int run = 0;
#pragma unroll
        for (int j = 0; j < 32; ++j) {
            int v = csum[j][b];
            csum[j][b] = run;
            run += v;
        }
        tot[b] = run;
    }
    __syncthreads();
    if (t == 0) {             // exclusive prefix over 32 bin totals (LDS)
        int run = 0;
#pragma unroll
        for (int j = 0; j < NBINS; ++j) { binbase[j] = run; run += tot[j]; }
        binbase[NBINS] = run;
    }
    __syncthreads();
    if (t <= NBINS) bstart[t] = binbase[t];

    int run = binbase[b] + csum[ch][b];
#pragma unroll
    for (int i = 0; i < 8; ++i) {
        offsets[(ch * 8 + i) * NBINS + b] = run;
        run += c[i];
    }
}

// ---- P3: scatter packed edge records into bucket segments ----
__global__ void part_scatter(const int* __restrict__ src, const int* __restrict__ dst,
                             int n_edges, const int* __restrict__ offsets,
                             u32* __restrict__ packed) {
    __shared__ int loff[NBINS];
    int t = threadIdx.x;
    if (t < NBINS) loff[t] = offsets[blockIdx.x * NBINS + t];
    __syncthreads();
    int per = (n_edges + gridDim.x - 1) / gridDim.x;
    int e0 = blockIdx.x * per;
    int e1 = min(e0 + per, n_edges);
    for (int e = e0 + t; e < e1; e += blockDim.x) {
        int d = dst[e];
        int pos = atomicAdd(&loff[d >> 13], 1);   // LDS atomic
        packed[pos] = ((u32)(d & (BSZ - 1)) << 18) | (u32)src[e];
    }
}

// ---- agg1: LDS histogram (sum of nf[src], count) per bucket slice ----
__global__ void __launch_bounds__(256) agg_pass1(const u32* __restrict__ packed,
                                                 const int* __restrict__ bstart,
                                                 const float* __restrict__ nf,
                                                 float* __restrict__ part1) {
    __shared__ float lsum[BSZ];
    __shared__ float lcnt[BSZ];
    int t = threadIdx.x;
    int b = blockIdx.x, s = blockIdx.y;
    for (int i = t; i < BSZ; i += 256) { lsum[i] = 0.0f; lcnt[i] = 0.0f; }
    __syncthreads();
    int st = bstart[b], en = bstart[b + 1];
    int per = (en - st + NSL - 1) / NSL;
    int e0 = st + s * per;
    int e1 = min(e0 + per, en);
    for (int e = e0 + t; e < e1; e += 256) {
        u32 p = packed[e];
        int local = (int)(p >> 18);
        int sc    = (int)(p & 0x3FFFFu);
        atomicAdd(&lsum[local], nf[sc]);
        atomicAdd(&lcnt[local], 1.0f);
    }
    __syncthreads();
    float* dp = part1 + ((size_t)(b * NSL + s) * 2) * BSZ;
    for (int i = t; i < BSZ; i += 256) { dp[i] = lsum[i]; dp[BSZ + i] = lcnt[i]; }
}

// ---- node1: reduce partials -> deg, hn; compute selfp, sp ----
__global__ void node1_x(const float* __restrict__ nf, const float* __restrict__ part1,
                        const float* __restrict__ w_s1, const float* __restrict__ w_n1,
                        const float* __restrict__ bb1,
                        const float* __restrict__ w_s2, const float* __restrict__ w_n2,
                        float* __restrict__ degf, float* __restrict__ selfp,
                        float* __restrict__ sp) {
    __shared__ float lws1[NHID], lwn1[NHID], lb1[NHID], lws2[NHID], lwn2[NHID];
    int tid = threadIdx.x;
    if (tid < NHID) {
        lws1[tid] = w_s1[tid];
        lwn1[tid] = w_n1[tid];
        lb1[tid]  = bb1[tid];
        lws2[tid] = w_s2[tid];
        lwn2[tid] = w_n2[tid];
    }
    __syncthreads();
    int v = blockIdx.x * blockDim.x + tid;
    int b = v >> 13, local = v & (BSZ - 1);
    float sum = 0.0f, cf = 0.0f;
#pragma unroll
    for (int s = 0; s < NSL; ++s) {
        const float* dp = part1 + ((size_t)(b * NSL + s) * 2) * BSZ;
        sum += dp[local];
        cf  += dp[BSZ + local];
    }
    float hn = sum / fmaxf(cf, 1.0f);
    float f = nf[v];
    float a = 0.0f, s2 = 0.0f;
#pragma unroll 8
    for (int j = 0; j < NHID; ++j) {
        float t = fast_tanh(fmaf(f, lws1[j], fmaf(hn, lwn1[j], lb1[j])));
        a  = fmaf(t, lws2[j], a);
        s2 = fmaf(t, lwn2[j], s2);
    }
    degf[v]  = cf;
    selfp[v] = a;
    sp[v]    = s2;
}

// ---- agg2: LDS histogram (sum of sp[src]) per bucket slice ----
__global__ void __launch_bounds__(256) agg_pass2(const u32* __restrict__ packed,
                                                 const int* __restrict__ bstart,
                                                 const float* __restrict__ spv,
                                                 float* __restrict__ part2) {
    __shared__ float lsum[BSZ];
    int t = threadIdx.x;
    int b = blockIdx.x, s = blockIdx.y;
    for (int i = t; i < BSZ; i += 256) lsum[i] = 0.0f;
    __syncthreads();
    int st = bstart[b], en = bstart[b + 1];
    int per = (en - st + NSL - 1) / NSL;
    int e0 = st + s * per;
    int e1 = min(e0 + per, en);
    for (int e = e0 + t; e < e1; e += 256) {
        u32 p = packed[e];
        atomicAdd(&lsum[p >> 18], spv[p & 0x3FFFFu]);
    }
    __syncthreads();
    float* dp = part2 + (size_t)(b * NSL + s) * BSZ;
    for (int i = t; i < BSZ; i += 256) dp[i] = lsum[i];
}

// ---- node2: reduce partials2; out1 (fp32); h2t K-major ----
__global__ void node2_x(const float* __restrict__ selfp, const float* __restrict__ part2,
                        const float* __restrict__ degf, const float* __restrict__ b2p,
                        float* __restrict__ out1, float* __restrict__ h2t) {
    int v = blockIdx.x * blockDim.x + threadIdx.x;
    int b = v >> 13, local = v & (BSZ - 1);
    float agg2 = 0.0f;
#pragma unroll
    for (int s = 0; s < NSL; ++s)
        agg2 += part2[(size_t)(b * NSL + s) * BSZ + local];
    float o = selfp[v] + agg2 / fmaxf(degf[v], 1.0f) + b2p[0];
    out1[v] = o;
    int r = v >> 12;     // graph (row) index 0..63
    int k = v & 4095;    // node-in-graph (K) index
    h2t[k * 64 + r] = fast_tanh(o);
}

// ---- GEMM (proven R9): 64x64 tile, readfirstlane A, dbuf A+B prefetch ----
__global__ void __launch_bounds__(256, 2) gemm_x(const float* __restrict__ h2t,
                                                 const float* __restrict__ w3,
                                                 float* __restrict__ Cpart) {
    int lane = threadIdx.x & 63;
    int wv   = threadIdx.x >> 6;
    int col  = blockIdx.x * 64 + lane;
    int k0   = blockIdx.y * KCH;
    int row0 = __builtin_amdgcn_readfirstlane(wv * 16);

    const float* Ap = h2t + (size_t)k0 * 64 + row0;
    const float* wp = w3 + (size_t)k0 * GK + col;

    float acc[16];
#pragma unroll
    for (int r = 0; r < 16; ++r) acc[r] = 0.0f;

    float bvA[8], bvB[8];
    float avA[16], avB[16];

#pragma unroll
    for (int j = 0; j < 8; ++j) bvA[j] = wp[(size_t)j * GK];
#pragma unroll
    for (int r = 0; r < 16; ++r) avA[r] = Ap[r];

    for (int kk = 0; kk < KCH; kk += 16) {
#pragma unroll
        for (int j = 0; j < 8; ++j) bvB[j] = wp[(size_t)(kk + 8 + j) * GK];
#pragma unroll
        for (int j = 0; j < 8; ++j) {
            const float* An = Ap + (size_t)(kk + j + 1) * 64;
            if ((j & 1) == 0) {
#pragma unroll
                for (int r = 0; r < 16; ++r) avB[r] = An[r];
                float b = bvA[j];
#pragma unroll
                for (int r = 0; r < 16; ++r) acc[r] = fmaf(avA[r], b, acc[r]);
            } else {
#pragma unroll
                for (int r = 0; r < 16; ++r) avA[r] = An[r];
                float b = bvA[j];
#pragma unroll
                for (int r = 0; r < 16; ++r) acc[r] = fmaf(avB[r], b, acc[r]);
            }
        }
        if (kk + 16 < KCH) {
#pragma unroll
            for (int j = 0; j < 8; ++j) bvA[j] = wp[(size_t)(kk + 16 + j) * GK];
        }
#pragma unroll
        for (int j = 0; j < 8; ++j) {
            int kn = kk + 8 + j + 1;
            if (kn > KCH - 1) kn = KCH - 1;
            const float* An = Ap + (size_t)kn * 64;
            if ((j & 1) == 0) {
#pragma unroll
                for (int r = 0; r < 16; ++r) avB[r] = An[r];
                float b = bvB[j];
#pragma unroll
                for (int r = 0; r < 16; ++r) acc[r] = fmaf(avA[r], b, acc[r]);
            } else {
#pragma unroll
                for (int r = 0; r < 16; ++r) avA[r] = An[r];
                float b = bvB[j];
#pragma unroll
                for (int r = 0; r < 16; ++r) acc[r] = fmaf(avB[r], b, acc[r]);
            }
        }
    }

    float* Cp = Cpart + (size_t)blockIdx.y * NTOT + (size_t)row0 * GK + col;
#pragma unroll
    for (int r = 0; r < 16; ++r) Cp[(size_t)r * GK] = acc[r];
}

// ---- reduce K-chunk partials + b3 -> out2 ----
__global__ void reduce_x(const float* __restrict__ Cpart, const float* __restrict__ b3,
                         float* __restrict__ out2) {
    int v = blockIdx.x * blockDim.x + threadIdx.x;
    float s = b3[v & 4095];
#pragma unroll
    for (int kc = 0; kc < KCHUNKS; ++kc) s += Cpart[(size_t)kc * NTOT + v];
    out2[v] = s;
}

// ================== FALLBACK PATH (proven R4 pipeline) ====================

__global__ void edge_pass1_f(const int* __restrict__ src, const int* __restrict__ dst,
                             const float* __restrict__ nf, float* __restrict__ agg,
                             float* __restrict__ deg, int n_edges) {
    int e = blockIdx.x * blockDim.x + threadIdx.x;
    if (e >= n_edges) return;
    int s = src[e], d = dst[e];
    atomicAdd(&agg[d], nf[s]);
    atomicAdd(&deg[d], 1.0f);
}

__global__ void node1_f(const float* __restrict__ nf, float* s0,
                        const float* __restrict__ deg,
                        const float* __restrict__ w_s1, const float* __restrict__ w_n1,
                        const float* __restrict__ bb1,
                        const float* __restrict__ w_s2, const float* __restrict__ w_n2,
                        float* __restrict__ sp) {
    __shared__ float lws1[NHID], lwn1[NHID], lb1[NHID], lws2[NHID], lwn2[NHID];
    int tid = threadIdx.x;
    if (tid < NHID) {
        lws1[tid] = w_s1[tid];
        lwn1[tid] = w_n1[tid];
        lb1[tid]  = bb1[tid];
        lws2[tid] = w_s2[tid];
        lwn2[tid] = w_n2[tid];
    }
    __syncthreads();
    int v = blockIdx.x * blockDim.x + tid;
    float f  = nf[v];
    float hn = s0[v] / fmaxf(deg[v], 1.0f);
    float a = 0.0f, s = 0.0f;
#pragma unroll 8
    for (int j = 0; j < NHID; ++j) {
        float t = fast_tanh(fmaf(f, lws1[j], fmaf(hn, lwn1[j], lb1[j])));
        a = fmaf(t, lws2[j], a);
        s = fmaf(t, lwn2[j], s);
    }
    s0[v] = a;
    sp[v] = s;
}

__global__ void edge_pass2_f(const int* __restrict__ src, const int* __restrict__ dst,
                             const float* __restrict__ sp, float* __restrict__ agg2,
                             int n_edges) {
    int e = blockIdx.x * blockDim.x + threadIdx.x;
    if (e >= n_edges) return;
    atomicAdd(&agg2[dst[e]], sp[src[e]]);
}

__global__ void node2_f(const float* __restrict__ s0, const float* __restrict__ agg2,
                        const float* __restrict__ deg, const float* __restrict__ b2p,
                        const float* __restrict__ b3p,
                        float* __restrict__ out1, float* __restrict__ h2t,
                        float* __restrict__ out2) {
    int v = blockIdx.x * blockDim.x + threadIdx.x;
    float o = s0[v] + agg2[v] / fmaxf(deg[v], 1.0f) + b2p[0];
    out1[v] = o;
    int r = v >> 12;
    int k = v & 4095;
    h2t[k * 64 + r] = fast_tanh(o);
    out2[v] = b3p[v & 4095];
}

__global__ void __launch_bounds__(256) gemm_f(const float* __restrict__ h2t,
                                              const float* __restrict__ w3,
                                              float* __restrict__ out2) {
    int n  = blockIdx.x * 256 + threadIdx.x;
    int k0 = blockIdx.y * KCH;
    float acc[64];
#pragma unroll
    for (int r = 0; r < 64; ++r) acc[r] = 0.0f;
    for (int k = k0; k < k0 + KCH; ++k) {
        float bv = w3[(size_t)k * GK + n];
        const float* Ak = h2t + k * 64;
#pragma unroll
        for (int r = 0; r < 64; ++r) acc[r] = fmaf(Ak[r], bv, acc[r]);
    }
#pragma unroll
    for (int r = 0; r < 64; ++r) atomicAdd(&out2[r * GK + n], acc[r]);
}

// ==========================================================================

extern "C" void kernel_launch(void* const* d_in, const int* in_sizes, int n_in,
                              void* d_out, int out_size, void* d_ws, size_t ws_size,
                              hipStream_t stream) {
    const float* nf  = (const float*)d_in[0];
    const int*   src = (const int*)d_in[1];
    const int*   dst = (const int*)d_in[2];
    const float* ws1 = (const float*)d_in[3];
    const float* wn1 = (const float*)d_in[4];
    const float* b1  = (const float*)d_in[5];
    const float* ws2 = (const float*)d_in[6];
    const float* wn2 = (const float*)d_in[7];
    const float* b2  = (const float*)d_in[8];
    const float* w3  = (const float*)d_in[9];
    const float* b3  = (const float*)d_in[10];
    float* out1 = (float*)d_out;
    float* out2 = (float*)d_out + NTOT;

    int n_edges = in_sizes[1];
    int eb = (n_edges + 255) / 256;

    if (ws_size >= (size_t)20 * 1024 * 1024 && n_edges <= (1 << 21)) {
        // -------- fast path: 20 MB layout --------
        char* base = (char*)d_ws;
        u32*   packed = (u32*)base;                              // [0, 8 MB)
        float* part   = (float*)(base + (((size_t)8) << 20));    // [8, 16 MB)
        float* degf   = (float*)(base + (((size_t)16) << 20));   // 1 MB
        float* selfp  = (float*)(base + (((size_t)17) << 20));   // 1 MB
        float* spbuf  = (float*)(base + (((size_t)18) << 20));   // sp -> h2t
        int*   counts = (int*)(base + (((size_t)19) << 20));           // 32 KB
        int*   offs   = (int*)(base + (((size_t)19) << 20) + 32768);   // 32 KB
        int*   bstart = (int*)(base + (((size_t)19) << 20) + 65536);   // 132 B
        float* h2t    = spbuf;          // alias: sp dead after agg_pass2
        float* Cpart  = (float*)base;   // 16 MB: packed+part dead after node2

        part_count  <<<PBLK, 256, 0, stream>>>(dst, n_edges, counts);
        part_scan   <<<1, 1024, 0, stream>>>(counts, offs, bstart);
        part_scatter<<<PBLK, 256, 0, stream>>>(src, dst, n_edges, offs, packed);
        agg_pass1<<<dim3(NBINS, NSL), 256, 0, stream>>>(packed, bstart, nf, part);
        node1_x<<<NTOT / 256, 256, 0, stream>>>(nf, part, ws1, wn1, b1, ws2, wn2,
                                                degf, selfp, spbuf);
        agg_pass2<<<dim3(NBINS, NSL), 256, 0, stream>>>(packed, bstart, spbuf, part);
        node2_x<<<NTOT / 256, 256, 0, stream>>>(selfp, part, degf, b2, out1, h2t);
        gemm_x<<<dim3(GK / 64, KCHUNKS), 256, 0, stream>>>(h2t, w3, Cpart);
        reduce_x<<<NTOT / 256, 256, 0, stream>>>(Cpart, b3, out2);
    } else {
        // -------- fallback: proven R4 pipeline (4.19 MB) --------
        float* ws = (float*)d_ws;
        float* S0 = ws;            // agg -> selfpart
        float* S1 = ws + 1 * NTOT; // deg
        float* S2 = ws + 2 * NTOT; // agg2
        float* S3 = ws + 3 * NTOT; // sp -> h2t

        (void)hipMemsetAsync(S0, 0, (size_t)3 * NTOT * sizeof(float), stream);
        edge_pass1_f<<<eb, 256, 0, stream>>>(src, dst, nf, S0, S1, n_edges);
        node1_f<<<NTOT / 256, 256, 0, stream>>>(nf, S0, S1, ws1, wn1, b1, ws2, wn2, S3);
        edge_pass2_f<<<eb, 256, 0, stream>>>(src, dst, S3, S2, n_edges);
        node2_f<<<NTOT / 256, 256, 0, stream>>>(S0, S2, S1, b2, b3, out1, S3, out2);
        gemm_f<<<dim3(GK / 256, KCHUNKS), 256, 0, stream>>>(S3, w3, out2);
    }
}